// Round 1
// baseline (136.587 us; speedup 1.0000x reference)
//
#include <hip/hip_runtime.h>

#define BATCH_SZ 8192
#define MAX_HIST 200
#define EMBED_F 64
#define WPB 4   // waves per block; one batch element per wave

__device__ __forceinline__ float4 f4add(float4 a, float4 b) {
    return make_float4(a.x + b.x, a.y + b.y, a.z + b.z, a.w + b.w);
}

// One batch element per WAVE (4 independent waves per 256-thread block).
// Within a wave: lane l -> g = l>>4 picks the row within a 4-row pack,
// s = l&15 picks the float4 column; one global_load_dwordx4 per lane =
// 4 full Y rows (1 KiB) per wave instruction.
// vs previous version (2 waves sharing one element): removes the final
// cross-wave LDS reduce + barrier, doubles per-wave pack count (~25 avg)
// so more time is spent in the deep 8-loads-in-flight tier, and makes the
// epilogue gathers (user/item/bu/bi/P/Q rows) wave-uniform (scalarizable).
__global__ __launch_bounds__(256) void svdpp_kernel(
    const int*   __restrict__ user,
    const int*   __restrict__ item,
    const int*   __restrict__ implicit,
    const int*   __restrict__ hist_len,
    const float* __restrict__ P,
    const float* __restrict__ Q,
    const float* __restrict__ Y,
    const float* __restrict__ bu,
    const float* __restrict__ bi,
    float*       __restrict__ out)
{
    __shared__ int lds_idx[WPB][MAX_HIST];

    const int w    = (int)(threadIdx.x >> 6);   // wave 0..3
    const int lane = (int)(threadIdx.x & 63);
    const int b    = (int)blockIdx.x * WPB + w; // this wave's batch element
    const int g = lane >> 4;
    const int s = lane & 15;

    const int L = max(hist_len[b], 1);

    // Stage this wave's 200 indices into its LDS slice (lanes 0..49, int4).
    const int* idx_row = implicit + (size_t)b * MAX_HIST;
    if (lane < MAX_HIST / 4) {
        int4 v = *reinterpret_cast<const int4*>(idx_row + lane * 4);
        *reinterpret_cast<int4*>(&lds_idx[w][lane * 4]) = v;
    }

    // Epilogue gathers issued early (independent of the LDS staging); all
    // wave-uniform rows, 16 distinct float4 addresses broadcast across lanes.
    const int u  = user[b];
    const int it = item[b];
    const float4 pu = reinterpret_cast<const float4*>(P)[(size_t)u  * 16 + s];
    const float4 qi = reinterpret_cast<const float4*>(Q)[(size_t)it * 16 + s];
    const float bub = bu[u];
    const float bib = bi[it];

    __syncthreads();   // staging -> gather visibility (waves touch own slice only)

    const float4* __restrict__ Y4 = reinterpret_cast<const float4*>(Y);
    const int* my_idx = lds_idx[w];

    const int full   = L >> 2;         // fully-valid packs
    const int npacks = (L + 3) >> 2;   // total packs incl. partial

    float4 acc = make_float4(0.f, 0.f, 0.f, 0.f);
    int p = 0;

    // Main tier: 8 packs (32 rows, 8 KiB) in flight.
    for (; p + 7 < full; p += 8) {
        float4 y[8];
        #pragma unroll
        for (int j = 0; j < 8; ++j) {
            const int i = my_idx[4 * (p + j) + g];
            y[j] = Y4[(size_t)i * 16 + s];
        }
        acc = f4add(acc, f4add(f4add(f4add(y[0], y[1]), f4add(y[2], y[3])),
                               f4add(f4add(y[4], y[5]), f4add(y[6], y[7]))));
    }
    // Mid tier: 4 packs in flight.
    for (; p + 3 < full; p += 4) {
        float4 y[4];
        #pragma unroll
        for (int j = 0; j < 4; ++j) {
            const int i = my_idx[4 * (p + j) + g];
            y[j] = Y4[(size_t)i * 16 + s];
        }
        acc = f4add(acc, f4add(f4add(y[0], y[1]), f4add(y[2], y[3])));
    }
    // Tail: one pack at a time; load always in-bounds (4p+g <= 199 and all
    // implicit[] slots hold valid item ids), predicate only the add.
    for (; p < npacks; ++p) {
        const int i = my_idx[4 * p + g];
        const float4 y = Y4[(size_t)i * 16 + s];
        if (4 * p + g < L) acc = f4add(acc, y);
    }

    // Reduce across the 4 row-groups within the wave (lane bits 4,5).
    #pragma unroll
    for (int off = 16; off < 64; off <<= 1) {
        acc.x += __shfl_xor(acc.x, off, 64);
        acc.y += __shfl_xor(acc.y, off, 64);
        acc.z += __shfl_xor(acc.z, off, 64);
        acc.w += __shfl_xor(acc.w, off, 64);
    }

    const float norm = 1.0f / sqrtf((float)L);
    float v = pu.x * (qi.x + norm * acc.x)
            + pu.y * (qi.y + norm * acc.y)
            + pu.z * (qi.z + norm * acc.z)
            + pu.w * (qi.w + norm * acc.w);

    // Reduce over the 16 float4 columns (lane bits 0..3).
    #pragma unroll
    for (int off = 1; off < 16; off <<= 1)
        v += __shfl_xor(v, off, 64);

    if (lane == 0)
        out[b] = 3.5f + bub + bib + v;
}

extern "C" void kernel_launch(void* const* d_in, const int* in_sizes, int n_in,
                              void* d_out, int out_size, void* d_ws, size_t ws_size,
                              hipStream_t stream) {
    const int*   user     = (const int*)  d_in[0];
    const int*   item     = (const int*)  d_in[1];
    const int*   implicit = (const int*)  d_in[2];
    const int*   hist_len = (const int*)  d_in[3];
    const float* P        = (const float*)d_in[4];
    const float* Q        = (const float*)d_in[5];
    const float* Y        = (const float*)d_in[6];
    const float* bu       = (const float*)d_in[7];
    const float* bi       = (const float*)d_in[8];
    float* out = (float*)d_out;

    svdpp_kernel<<<BATCH_SZ / WPB, 256, 0, stream>>>(
        user, item, implicit, hist_len, P, Q, Y, bu, bi, out);
}